// Round 10
// baseline (335.261 us; speedup 1.0000x reference)
//
#include <hip/hip_runtime.h>

#define B_ 64
#define N_ 196
#define D_ 768
#define H_ 3072
#define M_ (B_*N_)   // 12544
#define NP 256       // padded token count for attn GEMM K / M

typedef int int4v __attribute__((ext_vector_type(4)));
typedef signed char i8;

// ---- workspace layout ----
#define WS_MAX 0                 // float[8]: 0 n1w,1 attn,2 g1,3 n2,4 fc1,5 fc2,6 g2
#define WS_W1F 16
#define WS_B1F (16+768)
#define WS_G1F (16+768*2)
#define WS_W2F (16+768*3)
#define WS_B2F (16+768*4)
#define WS_G2F (16+768*5)
#define WS_BA  (16+768*6)        // int[256]
#define WS_BF1 (WS_BA+256)       // int[3072]
#define WS_BF2 (WS_BF1+3072)     // int[768]
// byte offsets. All GEMM operands are MFMA-fragment-linear:
//   [row/16][K/64][lane][16], lane=(row&15)+(((k>>4)&3)<<4), byte=k&15
#define OFF_WA   40960ull                      // frag, 256 rows, K=256 (zero-padded)
#define OFF_FC1  (OFF_WA+65536ull)             // frag, 3072 rows, K=768
#define OFF_FC2  (OFF_FC1+2359296ull)          // frag, 768 rows, K=3072
#define OFF_X2   (OFF_FC2+2359296ull)          // i8[12544][768] row-major
#define OFF_Q3   (OFF_X2+9633792ull)           // frag, 12544 rows, K=768  (q3F)
#define OFF_Q4   (OFF_Q3+9633792ull)           // frag, 12544 rows, K=3072 (q4F)
#define OFF_Q1T  OFF_Q4                        // frag q1T [b][48 d-groups][4][64][16] (aliases q4)

__device__ __forceinline__ float clamp8(float v){ return fminf(fmaxf(v,-128.f),127.f); }

__global__ void k_init(char* ws, const float* __restrict__ act, float* out_tail){
    int id = blockIdx.x*256 + threadIdx.x;
    if (blockIdx.x == 0){
        float* f = (float*)ws;
        if (threadIdx.x < 8) f[WS_MAX+threadIdx.x] = 0.f;
        if (threadIdx.x == 8) *out_tail = act[7];
    }
    if (id < 4096){ int4v z = {0,0,0,0}; ((int4v*)(ws+OFF_WA))[id] = z; }
}

__global__ void k_maxabs(const float* __restrict__ p0, const float* __restrict__ p1,
                         const float* __restrict__ p2, const float* __restrict__ p3,
                         const float* __restrict__ p4, const float* __restrict__ p5,
                         const float* __restrict__ p6, float* wsmax){
    const float* ps[7] = {p0,p1,p2,p3,p4,p5,p6};
    const int    n4s[7] = {192, 9604, 192, 192, 589824, 589824, 192};
    int tid = blockIdx.y;
    const float4* p = (const float4*)ps[tid]; int n4 = n4s[tid];
    float m = 0.f;
    for (int i = blockIdx.x*blockDim.x + threadIdx.x; i < n4; i += gridDim.x*blockDim.x){
        float4 v = p[i];
        m = fmaxf(m, fmaxf(fmaxf(fabsf(v.x),fabsf(v.y)), fmaxf(fabsf(v.z),fabsf(v.w))));
    }
    #pragma unroll
    for (int off = 32; off; off >>= 1) m = fmaxf(m, __shfl_down(m, off, 64));
    __shared__ float red[4];
    int lane = threadIdx.x & 63, wv = threadIdx.x >> 6;
    if (lane == 0) red[wv] = m;
    __syncthreads();
    if (threadIdx.x == 0){
        float mm = red[0];
        for (int w = 1; w < (int)blockDim.x/64; w++) mm = fmaxf(mm, red[w]);
        atomicMax((unsigned*)&wsmax[tid], __float_as_uint(mm));
    }
}

// fragment-linear offset for row o, k (K elems per row)
__device__ __forceinline__ size_t frag_off(int o, int k, int K){
    int g = o >> 4, c = k >> 6;
    int lane = (o & 15) + (((k >> 4) & 3) << 4);
    return (((size_t)g*(K>>6) + c)*64 + lane)*16 + (k & 15);
}

__global__ void k_qweights(const float* __restrict__ n1w, const float* __restrict__ n1b,
                           const float* __restrict__ aw,  const float* __restrict__ ab,
                           const float* __restrict__ g1w, const float* __restrict__ n2w,
                           const float* __restrict__ n2b, const float* __restrict__ f1w,
                           const float* __restrict__ f1b, const float* __restrict__ f2w,
                           const float* __restrict__ f2b, const float* __restrict__ g2w,
                           const float* __restrict__ act, char* ws){
    float* fws = (float*)ws;
    int*   iws = (int*)ws;
    const float* mx = fws + WS_MAX;
    long i = (long)blockIdx.x*blockDim.x + threadIdx.x;
    const long F4 = 589824;
    if (i < F4){ float sf = mx[4]/127.0f;
        float4 v = ((const float4*)f1w)[i];
        int o = (int)(i/192), kb = (int)(i%192)*4;
        unsigned b0 = (unsigned)(unsigned char)(i8)(int)fminf(fmaxf(rintf(v.x/sf),-128.f),127.f);
        unsigned b1 = (unsigned)(unsigned char)(i8)(int)fminf(fmaxf(rintf(v.y/sf),-128.f),127.f);
        unsigned b2 = (unsigned)(unsigned char)(i8)(int)fminf(fmaxf(rintf(v.z/sf),-128.f),127.f);
        unsigned b3 = (unsigned)(unsigned char)(i8)(int)fminf(fmaxf(rintf(v.w/sf),-128.f),127.f);
        *(unsigned*)(ws + OFF_FC1 + frag_off(o, kb, 768)) = b0 | (b1<<8) | (b2<<16) | (b3<<24);
        return; }
    i -= F4;
    if (i < F4){ float sf = mx[5]/127.0f;
        float4 v = ((const float4*)f2w)[i];
        int o = (int)(i/768), kb = (int)(i%768)*4;
        unsigned b0 = (unsigned)(unsigned char)(i8)(int)fminf(fmaxf(rintf(v.x/sf),-128.f),127.f);
        unsigned b1 = (unsigned)(unsigned char)(i8)(int)fminf(fmaxf(rintf(v.y/sf),-128.f),127.f);
        unsigned b2 = (unsigned)(unsigned char)(i8)(int)fminf(fmaxf(rintf(v.z/sf),-128.f),127.f);
        unsigned b3 = (unsigned)(unsigned char)(i8)(int)fminf(fmaxf(rintf(v.w/sf),-128.f),127.f);
        *(unsigned*)(ws + OFF_FC2 + frag_off(o, kb, 3072)) = b0 | (b1<<8) | (b2<<16) | (b3<<24);
        return; }
    i -= F4;
    if (i < 38416){ float sf = mx[1]/127.0f;
        int o = (int)(i/196), k = (int)(i%196);
        ((i8*)(ws+OFF_WA))[frag_off(o, k, NP)] =
            (i8)(int)fminf(fmaxf(rintf(aw[i]/sf),-128.f),127.f); return; }
    i -= 38416;
    if (i < 768){ float sf = mx[0]/127.0f; fws[WS_W1F+i] = rintf(n1w[i]/sf); return; }
    i -= 768;
    if (i < 768){ float sf = mx[0]/127.0f; fws[WS_B1F+i] = rintf(n1b[i]/(act[0]*sf)); return; }
    i -= 768;
    if (i < 768){ float sf = mx[2]/127.0f; fws[WS_G1F+i] = rintf(g1w[i]/sf); return; }
    i -= 768;
    if (i < 768){ float sf = mx[3]/127.0f; fws[WS_W2F+i] = rintf(n2w[i]/sf); return; }
    i -= 768;
    if (i < 768){ float sf = mx[3]/127.0f; fws[WS_B2F+i] = rintf(n2b[i]/(act[3]*sf)); return; }
    i -= 768;
    if (i < 768){ float sf = mx[6]/127.0f; fws[WS_G2F+i] = rintf(g2w[i]/sf); return; }
    i -= 768;
    if (i < 196){ float sf = mx[1]/127.0f; iws[WS_BA+i] = (int)rintf(ab[i]/(act[1]*sf)); return; }
    i -= 196;
    if (i < 3072){ float sf = mx[4]/127.0f; iws[WS_BF1+i] = (int)rintf(f1b[i]/(act[4]*sf)); return; }
    i -= 3072;
    if (i < 768){ float sf = mx[5]/127.0f; iws[WS_BF2+i] = (int)rintf(f2b[i]/(act[5]*sf)); return; }
}

// norm1 + quant_act1 -> q1T in B-fragment order: [b][d>>4][n>>6][lane][16]
__global__ __launch_bounds__(256) void k_stage1(const float* __restrict__ x,
                                                const char* __restrict__ wsc,
                                                char* __restrict__ ws,
                                                const float* __restrict__ act){
    __shared__ i8 T[64][80];
    const float* fws = (const float*)wsc;
    int b = blockIdx.z, n0 = blockIdx.y*64, d0 = blockIdx.x*64;
    int t = threadIdx.x;
    float a0 = act[0];
    float w1sf = fws[WS_MAX+0]/127.0f;
    float r1 = (a0*w1sf)/act[1];
    int dl = (t & 15) * 4;
    int d  = d0 + dl;
    float4 wv = *(const float4*)(fws + WS_W1F + d);
    float4 bv = *(const float4*)(fws + WS_B1F + d);
    #pragma unroll
    for (int pass = 0; pass < 4; pass++){
        int nl = (t >> 4) + pass*16;
        int n  = n0 + nl;
        i8 q[4] = {0,0,0,0};
        if (n < 196){
            float4 xv = *(const float4*)(x + ((size_t)b*196 + n)*768 + d);
            float o0 = rintf(xv.x/a0*wv.x + bv.x);
            float o1 = rintf(xv.y/a0*wv.y + bv.y);
            float o2 = rintf(xv.z/a0*wv.z + bv.z);
            float o3 = rintf(xv.w/a0*wv.w + bv.w);
            q[0] = (i8)(int)clamp8(rintf(o0*r1));
            q[1] = (i8)(int)clamp8(rintf(o1*r1));
            q[2] = (i8)(int)clamp8(rintf(o2*r1));
            q[3] = (i8)(int)clamp8(rintf(o3*r1));
        }
        T[dl+0][nl] = q[0]; T[dl+1][nl] = q[1];
        T[dl+2][nl] = q[2]; T[dl+3][nl] = q[3];
    }
    __syncthreads();
    i8* q1T = (i8*)(ws + OFF_Q1T) + (size_t)b*(48*4*1024);
    int gl = t >> 6, lane = t & 63;
    int d_loc = gl*16 + (lane & 15);
    int n16   = ((lane >> 4) & 3) * 16;
    int4v v = *(const int4v*)&T[d_loc][n16];
    size_t dst = (((size_t)((d0>>4)+gl)*4 + (n0>>6))*64 + lane)*16;
    *(int4v*)(q1T + dst) = v;
}

// Barrier-free direct-fragment int8 GEMM: both operands fragment-linear in
// global. 128x128 block tile, 4 waves (64x64 each), register double-buffer,
// NO LDS, NO __syncthreads -> compiler emits fine-grained vmcnt interleave.
// pa/pb pre-offset to wave's group base + lane*16. KC = K/64.
__device__ __forceinline__ void gemm_i8_direct_frag(const i8* pa, const i8* pb,
                                                    int KC, size_t sA, size_t sB,
                                                    int4v acc[4][4]){
    int4v a0[4], b0[4], a1[4], b1[4];
    #pragma unroll
    for (int mt=0;mt<4;mt++) a0[mt] = *(const int4v*)(pa + mt*sA);
    #pragma unroll
    for (int nt=0;nt<4;nt++) b0[nt] = *(const int4v*)(pb + nt*sB);
    for (int c = 0; c < KC; c += 2){
        #pragma unroll
        for (int mt=0;mt<4;mt++) a1[mt] = *(const int4v*)(pa + (c+1)*1024 + mt*sA);
        #pragma unroll
        for (int nt=0;nt<4;nt++) b1[nt] = *(const int4v*)(pb + (c+1)*1024 + nt*sB);
        #pragma unroll
        for (int mt=0;mt<4;mt++)
            #pragma unroll
            for (int nt=0;nt<4;nt++)
                acc[mt][nt] = __builtin_amdgcn_mfma_i32_16x16x64_i8(a0[mt], b0[nt], acc[mt][nt],0,0,0);
        if (c+2 < KC){
            #pragma unroll
            for (int mt=0;mt<4;mt++) a0[mt] = *(const int4v*)(pa + (c+2)*1024 + mt*sA);
            #pragma unroll
            for (int nt=0;nt<4;nt++) b0[nt] = *(const int4v*)(pb + (c+2)*1024 + nt*sB);
        }
        #pragma unroll
        for (int mt=0;mt<4;mt++)
            #pragma unroll
            for (int nt=0;nt<4;nt++)
                acc[mt][nt] = __builtin_amdgcn_mfma_i32_16x16x64_i8(a1[mt], b1[nt], acc[mt][nt],0,0,0);
    }
}

// attn: both operands fragment-linear, barrier-free K-loop (K=256).
// Epilogue writes x2 row-major + q3 in fragment-linear (fc1's A).
__global__ __launch_bounds__(256) void k_attn(const char* __restrict__ ws,
                                              const float* __restrict__ x,
                                              const float* __restrict__ act){
    __shared__ char smem[32768];
    const float* fws = (const float*)ws;
    const int*   iws = (const int*)ws;
    int b = blockIdx.z;
    int m0 = blockIdx.x*128, n0 = blockIdx.y*128;
    int t = threadIdx.x, lane = t & 63;
    int wm = (t>>6)&1, wn = t>>7;
    const i8* pa = (const i8*)(ws + OFF_WA)  + ((size_t)((m0>>4)+wm*4)*4)*1024 + lane*16;
    const i8* pb = (const i8*)(ws + OFF_Q1T) + (size_t)b*(48*4*1024)
                   + ((size_t)((n0>>4)+wn*4)*4)*1024 + lane*16;
    int4v acc[4][4]; int4v zz = {0,0,0,0};
    #pragma unroll
    for (int mt=0;mt<4;mt++) for (int nt=0;nt<4;nt++) acc[mt][nt] = zz;
    gemm_i8_direct_frag(pa, pb, 4, 4096, 4096, acc);

    float a0s=act[0], a1s=act[1], a2=act[2], a3=act[3], a4=act[4];
    float wasf = fws[WS_MAX+1]/127.0f; float r2  = (a1s*wasf)/a2;
    float g1sf = fws[WS_MAX+2]/127.0f; float r3a = (a2*g1sf)/a3; float r3b = a0s/a3;
    float w2sf = fws[WS_MAX+3]/127.0f; float r4  = (a3*w2sf)/a4;
    float g1v[4], w2v[4], b2v[4];
    #pragma unroll
    for (int nt=0;nt<4;nt++){
        int d = n0 + wn*64 + nt*16 + (lane&15);
        g1v[nt] = fws[WS_G1F + d]; w2v[nt] = fws[WS_W2F + d]; b2v[nt] = fws[WS_B2F + d];
    }
    i8* Xs = (i8*)smem;
    i8* Qs = (i8*)smem + 16384;
    i8* x2  = (i8*)(ws + OFF_X2);
    i8* q3F = (i8*)(ws + OFF_Q3);
    #pragma unroll
    for (int mt=0;mt<4;mt++){
        #pragma unroll
        for (int r=0;r<4;r++){
            int ml = wm*64 + mt*16 + (lane>>4)*4 + r;
            int o  = m0 + ml;
            int ba = iws[WS_BA + o];
            #pragma unroll
            for (int nt=0;nt<4;nt++){
                int nl = wn*64 + nt*16 + (lane&15);
                int d  = n0 + nl;
                float s2 = (float)(acc[mt][nt][r] + ba);
                float q2 = clamp8(rintf(s2*r2));
                float o3v = q2*g1v[nt];
                float xv = (o < 196) ? x[((size_t)b*196 + o)*768 + d] : 0.f;
                float idi = rintf(xv/a0s);
                float tt = rintf(o3v*r3a) + rintf(idi*r3b);
                tt = clamp8(tt);
                float o4 = tt*w2v[nt] + b2v[nt];
                float qr = clamp8(rintf(o4*r4));
                Xs[ml*128 + nl] = (i8)(int)tt;
                Qs[ml*128 + nl] = (i8)(int)qr;
            }
        }
    }
    __syncthreads();
    #pragma unroll
    for (int e=0;e<4;e++){
        int id = t + e*256;
        int row = id>>3, c = id&7;
        int o = m0 + row;
        if (o < 196){
            size_t g = ((size_t)b*196 + o)*768 + n0 + c*16;
            *(int4v*)(x2 + g) = *(const int4v*)(Xs + row*128 + c*16);
            // q3 fragment-linear: global flattened row r, k = n0 + c*16
            int r2i = b*196 + o;
            int lane_d = (r2i & 15) + ((c & 3) << 4);
            size_t dst = (((size_t)(r2i>>4))*12 + (size_t)(n0>>6) + (c>>2))*1024
                         + (size_t)lane_d*16;
            *(int4v*)(q3F + dst) = *(const int4v*)(Qs + row*128 + c*16);
        }
    }
}

// fc1: q3F x fc1F -> relu -> quant -> q4F (fragment-linear, K=3072 for fc2).
// Barrier-free mainloop; LDS only for epilogue repack.
__global__ __launch_bounds__(256) void k_fc1(const char* __restrict__ ws, const float* __restrict__ act){
    __shared__ char smem[16384];
    const float* fws = (const float*)ws;
    const int*   iws = (const int*)ws;
    int m0 = blockIdx.x*128, n0 = blockIdx.y*128;
    int t = threadIdx.x, lane = t & 63;
    int wm = (t>>6)&1, wn = t>>7;
    const i8* pa = (const i8*)(ws+OFF_Q3)  + ((size_t)(m0>>4) + wm*4)*(12*1024) + (size_t)lane*16;
    const i8* pb = (const i8*)(ws+OFF_FC1) + ((size_t)(n0>>4) + wn*4)*(12*1024) + (size_t)lane*16;
    const int* bias = iws + WS_BF1;
    i8* q4F = (i8*)(ws+OFF_Q4);
    int4v acc[4][4]; int4v zz = {0,0,0,0};
    #pragma unroll
    for (int mt=0;mt<4;mt++) for (int nt=0;nt<4;nt++) acc[mt][nt] = zz;
    gemm_i8_direct_frag(pa, pb, 12, 12*1024, 12*1024, acc);
    float wsf = fws[WS_MAX+4]/127.0f;
    float r5 = (act[4]*wsf)/act[5];
    int bcol[4];
    #pragma unroll
    for (int nt=0;nt<4;nt++) bcol[nt] = bias[n0 + wn*64 + nt*16 + (lane&15)];
    i8* Cs = (i8*)smem;
    #pragma unroll
    for (int mt=0;mt<4;mt++){
        #pragma unroll
        for (int nt=0;nt<4;nt++){
            int nl = wn*64 + nt*16 + (lane&15);
            #pragma unroll
            for (int r=0;r<4;r++){
                int s = acc[mt][nt][r] + bcol[nt];
                if (s < 0) s = 0;
                float q = clamp8(rintf((float)s * r5));
                int ml = wm*64 + mt*16 + (lane>>4)*4 + r;
                Cs[ml*128 + nl] = (i8)(int)q;
            }
        }
    }
    __syncthreads();
    // write q4 fragment-linear (row group mg, k-chunk kc2), coalesced 1KB per (mg,kc2)
    #pragma unroll
    for (int e=0;e<4;e++){
        int id = t + e*256;            // 0..1023
        int mg  = id >> 7;             // 0..7
        int kc2 = (id >> 6) & 1;       // 0..1
        int ld  = id & 63;
        int row = mg*16 + (ld & 15);
        int cb  = kc2*64 + ((ld>>4)&3)*16;
        int4v v = *(const int4v*)(Cs + row*128 + cb);
        size_t dst = (((size_t)(m0>>4) + mg)*48 + (size_t)(n0>>6) + kc2)*1024 + (size_t)ld*16;
        *(int4v*)(q4F + dst) = v;
    }
}

// fc2: q4F x fc2F -> quant -> gamma2 -> +identity -> final quant -> fp32.
// Fully barrier-free, zero LDS.
__global__ __launch_bounds__(256) void k_fc2(const char* __restrict__ ws, const float* __restrict__ act,
                                             float* __restrict__ out){
    const float* fws = (const float*)ws;
    const int*   iws = (const int*)ws;
    int m0 = blockIdx.x*128, n0 = blockIdx.y*128;
    int t = threadIdx.x, lane = t & 63;
    int wm = (t>>6)&1, wn = t>>7;
    const i8* pa = (const i8*)(ws+OFF_Q4)  + ((size_t)(m0>>4) + wm*4)*(48*1024) + (size_t)lane*16;
    const i8* pb = (const i8*)(ws+OFF_FC2) + ((size_t)(n0>>4) + wn*4)*(48*1024) + (size_t)lane*16;
    const int* bias = iws + WS_BF2;
    const float* g2f = fws + WS_G2F;
    const i8* x2 = (const i8*)(ws+OFF_X2);
    int4v acc[4][4]; int4v zz = {0,0,0,0};
    #pragma unroll
    for (int mt=0;mt<4;mt++) for (int nt=0;nt<4;nt++) acc[mt][nt] = zz;
    gemm_i8_direct_frag(pa, pb, 48, 48*1024, 48*1024, acc);
    float a3=act[3], a5=act[5], a6=act[6], a7=act[7];
    float wsf  = fws[WS_MAX+5]/127.0f; float r6  = (a5*wsf)/a6;
    float g2sf = fws[WS_MAX+6]/127.0f; float r7a = (a6*g2sf)/a7; float r7b = a3/a7;
    int bcol[4]; float g2v[4];
    #pragma unroll
    for (int nt=0;nt<4;nt++){
        int nc = n0 + wn*64 + nt*16 + (lane&15);
        bcol[nt] = bias[nc]; g2v[nt] = g2f[nc];
    }
    #pragma unroll
    for (int mt=0;mt<4;mt++){
        #pragma unroll
        for (int nt=0;nt<4;nt++){
            int nc = n0 + wn*64 + nt*16 + (lane&15);
            #pragma unroll
            for (int r=0;r<4;r++){
                int ml = wm*64 + mt*16 + (lane>>4)*4 + r;
                size_t gi = (size_t)(m0+ml)*768 + nc;
                int s = acc[mt][nt][r] + bcol[nt];
                float q6 = clamp8(rintf((float)s*r6));
                float o7 = q6*g2v[nt];
                float idi = (float)x2[gi];
                float tt = rintf(o7*r7a) + rintf(idi*r7b);
                tt = clamp8(tt);
                out[gi] = tt*a7;
            }
        }
    }
}

extern "C" void kernel_launch(void* const* d_in, const int* in_sizes, int n_in,
                              void* d_out, int out_size, void* d_ws, size_t ws_size,
                              hipStream_t stream){
    const float* x   = (const float*)d_in[0];
    const float* n1w = (const float*)d_in[1];
    const float* n1b = (const float*)d_in[2];
    const float* aw  = (const float*)d_in[3];
    const float* ab  = (const float*)d_in[4];
    const float* g1w = (const float*)d_in[5];
    const float* n2w = (const float*)d_in[6];
    const float* n2b = (const float*)d_in[7];
    const float* f1w = (const float*)d_in[8];
    const float* f1b = (const float*)d_in[9];
    const float* f2w = (const float*)d_in[10];
    const float* f2b = (const float*)d_in[11];
    const float* g2w = (const float*)d_in[12];
    const float* act = (const float*)d_in[13];
    char* ws = (char*)d_ws;
    float* out = (float*)d_out;

    k_init<<<16,256,0,stream>>>(ws, act, out + (size_t)B_*N_*D_);
    k_maxabs<<<dim3(120,7),256,0,stream>>>(n1w, aw, g1w, n2w, f1w, f2w, g2w, (float*)ws);
    long qwThreads = 2L*589824 + 38416 + 768L*6 + 196 + 3072 + 768;
    k_qweights<<<(int)((qwThreads+255)/256),256,0,stream>>>(n1w,n1b,aw,ab,g1w,n2w,n2b,
                                                            f1w,f1b,f2w,f2b,g2w,act,ws);
    k_stage1<<<dim3(12,4,64),256,0,stream>>>(x, ws, ws, act);
    k_attn<<<dim3(2,6,64),256,0,stream>>>(ws, x, act);
    k_fc1<<<dim3(98,24),256,0,stream>>>(ws, act);
    k_fc2<<<dim3(98,6),256,0,stream>>>(ws, act, out);
}

// Round 11
// 272.550 us; speedup vs baseline: 1.2301x; 1.2301x over previous
//
#include <hip/hip_runtime.h>

#define B_ 64
#define N_ 196
#define D_ 768
#define H_ 3072
#define M_ (B_*N_)   // 12544
#define NP 256       // padded token count for attn GEMM K / M

typedef int int4v __attribute__((ext_vector_type(4)));
typedef signed char i8;

// ---- workspace layout ----
#define WS_MAX 0                 // float[8]: 0 n1w,1 attn,2 g1,3 n2,4 fc1,5 fc2,6 g2
#define WS_W1F 16
#define WS_B1F (16+768)
#define WS_G1F (16+768*2)
#define WS_W2F (16+768*3)
#define WS_B2F (16+768*4)
#define WS_G2F (16+768*5)
#define WS_BA  (16+768*6)        // int[256]
#define WS_BF1 (WS_BA+256)       // int[3072]
#define WS_BF2 (WS_BF1+3072)     // int[768]
// byte offsets
#define OFF_WA   40960ull                      // i8[256][256] zero-padded attn weight
#define OFF_FC1  (OFF_WA+65536ull)             // i8[3072][768]
#define OFF_FC2  (OFF_FC1+2359296ull)          // i8[768][3072]
#define OFF_X2   (OFF_FC2+2359296ull)          // i8[12544][768]
#define OFF_Q3   (OFF_X2+9633792ull)           // i8[12544][768]
#define OFF_Q4   (OFF_Q3+9633792ull)           // i8[12544][3072]
// q1T and x8 alias the q4 region (lifetime-disjoint: both fully consumed by
// attn BEFORE fc1 writes q4). q1T = 12.58 MB, x8 = 9.63 MB, q4 = 38.5 MB.
#define OFF_Q1T  OFF_Q4                        // i8[64][768][256]
#define OFF_X8   (OFF_Q4+12582912ull)          // i8[12544][768] int8 identity rint(x/a0)

__device__ __forceinline__ float clamp8(float v){ return fminf(fmaxf(v,-128.f),127.f); }

// async global->LDS, 16B per lane. lds dest = wave-uniform base + lane*16.
__device__ __forceinline__ void async16(const void* g, void* l){
    __builtin_amdgcn_global_load_lds((const __attribute__((address_space(1))) void*)g,
                                     (__attribute__((address_space(3))) void*)l, 16, 0, 0);
}

__global__ void k_init(char* ws, const float* __restrict__ act, float* out_tail){
    int id = blockIdx.x*256 + threadIdx.x;
    if (blockIdx.x == 0){
        float* f = (float*)ws;
        if (threadIdx.x < 8) f[WS_MAX+threadIdx.x] = 0.f;
        if (threadIdx.x == 8) *out_tail = act[7];
    }
    if (id < 4096){ int4v z = {0,0,0,0}; ((int4v*)(ws+OFF_WA))[id] = z; }
}

__global__ void k_maxabs(const float* __restrict__ p0, const float* __restrict__ p1,
                         const float* __restrict__ p2, const float* __restrict__ p3,
                         const float* __restrict__ p4, const float* __restrict__ p5,
                         const float* __restrict__ p6, float* wsmax){
    const float* ps[7] = {p0,p1,p2,p3,p4,p5,p6};
    const int    n4s[7] = {192, 9604, 192, 192, 589824, 589824, 192};
    int tid = blockIdx.y;
    const float4* p = (const float4*)ps[tid]; int n4 = n4s[tid];
    float m = 0.f;
    for (int i = blockIdx.x*blockDim.x + threadIdx.x; i < n4; i += gridDim.x*blockDim.x){
        float4 v = p[i];
        m = fmaxf(m, fmaxf(fmaxf(fabsf(v.x),fabsf(v.y)), fmaxf(fabsf(v.z),fabsf(v.w))));
    }
    #pragma unroll
    for (int off = 32; off; off >>= 1) m = fmaxf(m, __shfl_down(m, off, 64));
    __shared__ float red[4];
    int lane = threadIdx.x & 63, wv = threadIdx.x >> 6;
    if (lane == 0) red[wv] = m;
    __syncthreads();
    if (threadIdx.x == 0){
        float mm = red[0];
        for (int w = 1; w < (int)blockDim.x/64; w++) mm = fmaxf(mm, red[w]);
        atomicMax((unsigned*)&wsmax[tid], __float_as_uint(mm));
    }
}

__global__ void k_qweights(const float* __restrict__ n1w, const float* __restrict__ n1b,
                           const float* __restrict__ aw,  const float* __restrict__ ab,
                           const float* __restrict__ g1w, const float* __restrict__ n2w,
                           const float* __restrict__ n2b, const float* __restrict__ f1w,
                           const float* __restrict__ f1b, const float* __restrict__ f2w,
                           const float* __restrict__ f2b, const float* __restrict__ g2w,
                           const float* __restrict__ act, char* ws){
    float* fws = (float*)ws;
    int*   iws = (int*)ws;
    const float* mx = fws + WS_MAX;
    long i = (long)blockIdx.x*blockDim.x + threadIdx.x;
    const long F4 = 589824;
    if (i < F4){ float sf = mx[4]/127.0f;
        float4 v = ((const float4*)f1w)[i];
        char4 o = make_char4(
            (i8)(int)fminf(fmaxf(rintf(v.x/sf),-128.f),127.f),
            (i8)(int)fminf(fmaxf(rintf(v.y/sf),-128.f),127.f),
            (i8)(int)fminf(fmaxf(rintf(v.z/sf),-128.f),127.f),
            (i8)(int)fminf(fmaxf(rintf(v.w/sf),-128.f),127.f));
        ((char4*)(ws+OFF_FC1))[i] = o; return; }
    i -= F4;
    if (i < F4){ float sf = mx[5]/127.0f;
        float4 v = ((const float4*)f2w)[i];
        char4 o = make_char4(
            (i8)(int)fminf(fmaxf(rintf(v.x/sf),-128.f),127.f),
            (i8)(int)fminf(fmaxf(rintf(v.y/sf),-128.f),127.f),
            (i8)(int)fminf(fmaxf(rintf(v.z/sf),-128.f),127.f),
            (i8)(int)fminf(fmaxf(rintf(v.w/sf),-128.f),127.f));
        ((char4*)(ws+OFF_FC2))[i] = o; return; }
    i -= F4;
    if (i < 38416){ float sf = mx[1]/127.0f;
        int o = (int)(i/196), k = (int)(i%196);
        ((i8*)(ws+OFF_WA))[o*NP+k] = (i8)(int)fminf(fmaxf(rintf(aw[i]/sf),-128.f),127.f); return; }
    i -= 38416;
    if (i < 768){ float sf = mx[0]/127.0f; fws[WS_W1F+i] = rintf(n1w[i]/sf); return; }
    i -= 768;
    if (i < 768){ float sf = mx[0]/127.0f; fws[WS_B1F+i] = rintf(n1b[i]/(act[0]*sf)); return; }
    i -= 768;
    if (i < 768){ float sf = mx[2]/127.0f; fws[WS_G1F+i] = rintf(g1w[i]/sf); return; }
    i -= 768;
    if (i < 768){ float sf = mx[3]/127.0f; fws[WS_W2F+i] = rintf(n2w[i]/sf); return; }
    i -= 768;
    if (i < 768){ float sf = mx[3]/127.0f; fws[WS_B2F+i] = rintf(n2b[i]/(act[3]*sf)); return; }
    i -= 768;
    if (i < 768){ float sf = mx[6]/127.0f; fws[WS_G2F+i] = rintf(g2w[i]/sf); return; }
    i -= 768;
    if (i < 196){ float sf = mx[1]/127.0f; iws[WS_BA+i] = (int)rintf(ab[i]/(act[1]*sf)); return; }
    i -= 196;
    if (i < 3072){ float sf = mx[4]/127.0f; iws[WS_BF1+i] = (int)rintf(f1b[i]/(act[4]*sf)); return; }
    i -= 3072;
    if (i < 768){ float sf = mx[5]/127.0f; iws[WS_BF2+i] = (int)rintf(f2b[i]/(act[5]*sf)); return; }
}

// norm1 + quant_act1 -> q1T int8 [b][d][n] (n padded to 256), via LDS transpose.
// Also emits x8 = rint(x/a0) int8 row-major (exact: input is pre-quantized).
__global__ __launch_bounds__(256) void k_stage1(const float* __restrict__ x,
                                                const char* __restrict__ wsc,
                                                char* __restrict__ ws,
                                                const float* __restrict__ act){
    __shared__ i8 T[64][68];
    const float* fws = (const float*)wsc;
    int b = blockIdx.z, n0 = blockIdx.y*64, d0 = blockIdx.x*64;
    int t = threadIdx.x;
    float a0 = act[0];
    float w1sf = fws[WS_MAX+0]/127.0f;
    float r1 = (a0*w1sf)/act[1];
    int dl = (t & 15) * 4;
    int d  = d0 + dl;
    float4 wv = *(const float4*)(fws + WS_W1F + d);
    float4 bv = *(const float4*)(fws + WS_B1F + d);
    i8* x8 = (i8*)(ws + OFF_X8);
    #pragma unroll
    for (int pass = 0; pass < 4; pass++){
        int nl = (t >> 4) + pass*16;
        int n  = n0 + nl;
        i8 q[4] = {0,0,0,0};
        if (n < 196){
            float4 xv = *(const float4*)(x + ((size_t)b*196 + n)*768 + d);
            float i0 = rintf(xv.x/a0), i1 = rintf(xv.y/a0);
            float i2 = rintf(xv.z/a0), i3 = rintf(xv.w/a0);
            *(char4*)(x8 + ((size_t)b*196 + n)*768 + d) =
                make_char4((i8)(int)i0,(i8)(int)i1,(i8)(int)i2,(i8)(int)i3);
            float o0 = rintf(i0*wv.x + bv.x);
            float o1 = rintf(i1*wv.y + bv.y);
            float o2 = rintf(i2*wv.z + bv.z);
            float o3 = rintf(i3*wv.w + bv.w);
            q[0] = (i8)(int)clamp8(rintf(o0*r1));
            q[1] = (i8)(int)clamp8(rintf(o1*r1));
            q[2] = (i8)(int)clamp8(rintf(o2*r1));
            q[3] = (i8)(int)clamp8(rintf(o3*r1));
        }
        T[dl+0][nl] = q[0]; T[dl+1][nl] = q[1];
        T[dl+2][nl] = q[2]; T[dl+3][nl] = q[3];
    }
    __syncthreads();
    i8* q1T = (i8*)(ws + OFF_Q1T) + (size_t)b*768*NP;
    #pragma unroll
    for (int e = 0; e < 4; e++){
        int id = t + e*256;
        int row = id >> 4, c = (id & 15) * 4;
        int v = *(const int*)&T[row][c];
        *(int*)(q1T + (size_t)(d0+row)*NP + n0 + c) = v;
    }
}

// 4-wave double-buffered int8 GEMM mainloop (used by attn): 128x128 tile, BK=64,
// one barrier per iter.
__device__ __forceinline__ void gemm_i8_dbuf(const i8* __restrict__ qa, const i8* __restrict__ wb,
                                             size_t lda, size_t ldb,
                                             int m0, int n0, int K, int4v acc[4][4],
                                             i8* As, i8* Bs, int t){
    int lane = t & 63;
    int w = t >> 6;
    int wm = w & 1, wn = w >> 1;
    int lr = lane >> 2, lc = lane & 3;
    const i8* ga = qa + (size_t)(m0 + w*32 + lr)*lda + lc*16;
    const i8* gb = wb + (size_t)(n0 + w*32 + lr)*ldb + lc*16;
    int loff = (w*32 + lr)*64 + lc*16;
    async16(ga,            As + loff);
    async16(ga + 16*lda,   As + loff + 16*64);
    async16(gb,            Bs + loff);
    async16(gb + 16*ldb,   Bs + loff + 16*64);
    int iters = K >> 6;
    for (int i = 0; i < iters; i++){
        __syncthreads();
        if (i+1 < iters){
            int kb = (i+1) << 6;
            int nb = ((i+1)&1) << 13;
            async16(ga + kb,            As + nb + loff);
            async16(ga + kb + 16*lda,   As + nb + loff + 16*64);
            async16(gb + kb,            Bs + nb + loff);
            async16(gb + kb + 16*ldb,   Bs + nb + loff + 16*64);
        }
        int cb = (i&1) << 13;
        int4v a[4], bb[4];
        #pragma unroll
        for (int mt = 0; mt < 4; mt++)
            a[mt] = *(const int4v*)(As + cb + (wm*64+mt*16+(lane&15))*64 + (lane>>4)*16);
        #pragma unroll
        for (int nt = 0; nt < 4; nt++)
            bb[nt] = *(const int4v*)(Bs + cb + (wn*64+nt*16+(lane&15))*64 + (lane>>4)*16);
        #pragma unroll
        for (int mt = 0; mt < 4; mt++)
            #pragma unroll
            for (int nt = 0; nt < 4; nt++)
                acc[mt][nt] = __builtin_amdgcn_mfma_i32_16x16x64_i8(a[mt], bb[nt], acc[mt][nt], 0,0,0);
    }
}

// 8-wave (512-thread) double-buffered int8 GEMM: 128x128 tile, BK=64, wave tile
// 64x32 (2m x 4n wave grid). One async16 per thread per operand per iter.
// acc[4][2]. One barrier per iter.
__device__ __forceinline__ void gemm_i8_512(const i8* __restrict__ qa, const i8* __restrict__ wb,
                                            size_t lda, size_t ldb,
                                            int m0, int n0, int K, int4v acc[4][2],
                                            i8* As, i8* Bs, int t){
    int lane = t & 63;
    int w = t >> 6;                 // 0..7
    int wm = w & 1, wn = w >> 1;    // wm: 2 m-halves, wn: 4 n-quarters
    int sr = t >> 2, sc = t & 3;    // staging: 128 rows x 4 chunks
    const i8* ga = qa + (size_t)(m0 + sr)*lda + sc*16;
    const i8* gb = wb + (size_t)(n0 + sr)*ldb + sc*16;
    int loff = sr*64 + sc*16;       // == 1024*w + lane*16 (wave-uniform + lane*16)
    async16(ga, As + loff);
    async16(gb, Bs + loff);
    int arow = (wm*64 + (lane&15))*64 + (lane>>4)*16;
    int brow = (wn*32 + (lane&15))*64 + (lane>>4)*16;
    int iters = K >> 6;
    for (int i = 0; i < iters; i++){
        __syncthreads();
        if (i+1 < iters){
            int kb = (i+1) << 6;
            int nb = ((i+1)&1) << 13;
            async16(ga + kb, As + nb + loff);
            async16(gb + kb, Bs + nb + loff);
        }
        int cb = (i&1) << 13;
        int4v a[4], bb[2];
        #pragma unroll
        for (int mt = 0; mt < 4; mt++)
            a[mt] = *(const int4v*)(As + cb + arow + mt*16*64);
        #pragma unroll
        for (int nt = 0; nt < 2; nt++)
            bb[nt] = *(const int4v*)(Bs + cb + brow + nt*16*64);
        #pragma unroll
        for (int mt = 0; mt < 4; mt++)
            #pragma unroll
            for (int nt = 0; nt < 2; nt++)
                acc[mt][nt] = __builtin_amdgcn_mfma_i32_16x16x64_i8(a[mt], bb[nt], acc[mt][nt], 0,0,0);
    }
}

// attn as int8 MFMA GEMM + fused epilogue chain (4 waves). Identity from x8 int8.
__global__ __launch_bounds__(256) void k_attn(const char* __restrict__ ws,
                                              const float* __restrict__ act){
    __shared__ char smem[32768];
    const float* fws = (const float*)ws;
    const int*   iws = (const int*)ws;
    const i8* A  = (const i8*)(ws + OFF_WA);
    const i8* Bq = (const i8*)(ws + OFF_Q1T) + (size_t)blockIdx.z*768*NP;
    const i8* x8 = (const i8*)(ws + OFF_X8);
    i8* x2 = (i8*)(ws + OFF_X2);
    i8* q3 = (i8*)(ws + OFF_Q3);
    int b = blockIdx.z;
    int m0 = blockIdx.x*128, n0 = blockIdx.y*128;
    int t = threadIdx.x, lane = t & 63;
    int wm = (t>>6)&1, wn = t>>7;
    int4v acc[4][4]; int4v zz = {0,0,0,0};
    #pragma unroll
    for (int mt=0;mt<4;mt++) for (int nt=0;nt<4;nt++) acc[mt][nt] = zz;
    gemm_i8_dbuf(A, Bq, NP, NP, m0, n0, NP, acc, (i8*)smem, (i8*)smem+16384, t);

    float a1=act[1], a2=act[2], a3=act[3], a4=act[4];
    float wasf = fws[WS_MAX+1]/127.0f; float r2  = (a1*wasf)/a2;
    float g1sf = fws[WS_MAX+2]/127.0f; float r3a = (a2*g1sf)/a3; float r3b = act[0]/a3;
    float w2sf = fws[WS_MAX+3]/127.0f; float r4  = (a3*w2sf)/a4;
    float g1v[4], w2v[4], b2v[4];
    #pragma unroll
    for (int nt=0;nt<4;nt++){
        int d = n0 + wn*64 + nt*16 + (lane&15);
        g1v[nt] = fws[WS_G1F + d]; w2v[nt] = fws[WS_W2F + d]; b2v[nt] = fws[WS_B2F + d];
    }
    __syncthreads();
    i8* Xs = (i8*)smem;
    i8* Qs = (i8*)smem + 16384;
    #pragma unroll
    for (int mt=0;mt<4;mt++){
        #pragma unroll
        for (int r=0;r<4;r++){
            int ml = wm*64 + mt*16 + (lane>>4)*4 + r;
            int o  = m0 + ml;
            int ba = iws[WS_BA + o];
            #pragma unroll
            for (int nt=0;nt<4;nt++){
                int nl = wn*64 + nt*16 + (lane&15);
                int d  = n0 + nl;
                float s2 = (float)(acc[mt][nt][r] + ba);
                float q2 = clamp8(rintf(s2*r2));
                float o3v = q2*g1v[nt];
                float idi = (o < 196) ? (float)x8[((size_t)b*196 + o)*768 + d] : 0.f;
                float tt = rintf(o3v*r3a) + rintf(idi*r3b);
                tt = clamp8(tt);
                float o4 = tt*w2v[nt] + b2v[nt];
                float qr = clamp8(rintf(o4*r4));
                Xs[ml*128 + nl] = (i8)(int)tt;
                Qs[ml*128 + nl] = (i8)(int)qr;
            }
        }
    }
    __syncthreads();
    #pragma unroll
    for (int e=0;e<4;e++){
        int id = t + e*256;
        int row = id>>3, c = id&7;
        int o = m0 + row;
        if (o < 196){
            size_t g = ((size_t)b*196 + o)*768 + n0 + c*16;
            *(int4v*)(x2 + g) = *(const int4v*)(Xs + row*128 + c*16);
            *(int4v*)(q3 + g) = *(const int4v*)(Qs + row*128 + c*16);
        }
    }
}

// fc1: q3[12544,768] x fc1_int[3072,768]^T -> relu -> quant -> q4 int8. 512 threads.
__global__ __launch_bounds__(512) void k_fc1(const char* __restrict__ ws, const float* __restrict__ act){
    __shared__ char smem[32768];
    const float* fws = (const float*)ws;
    const int*   iws = (const int*)ws;
    const i8* qa = (const i8*)(ws+OFF_Q3);
    const i8* wb = (const i8*)(ws+OFF_FC1);
    const int* bias = iws + WS_BF1;
    i8* qout = (i8*)(ws+OFF_Q4);
    int m0 = blockIdx.x*128, n0 = blockIdx.y*128;
    int t = threadIdx.x, lane = t & 63;
    int w = t >> 6, wm = w & 1, wn = w >> 1;
    int4v acc[4][2]; int4v zz = {0,0,0,0};
    #pragma unroll
    for (int mt=0;mt<4;mt++) for (int nt=0;nt<2;nt++) acc[mt][nt] = zz;
    gemm_i8_512(qa, wb, 768, 768, m0, n0, 768, acc, (i8*)smem, (i8*)smem+16384, t);
    float wsf = fws[WS_MAX+4]/127.0f;
    float r5 = (act[4]*wsf)/act[5];
    int bcol[2];
    #pragma unroll
    for (int nt=0;nt<2;nt++) bcol[nt] = bias[n0 + wn*32 + nt*16 + (lane&15)];
    __syncthreads();
    i8* Cs = (i8*)smem;
    #pragma unroll
    for (int mt=0;mt<4;mt++){
        #pragma unroll
        for (int nt=0;nt<2;nt++){
            int nl = wn*32 + nt*16 + (lane&15);
            #pragma unroll
            for (int r=0;r<4;r++){
                int s = acc[mt][nt][r] + bcol[nt];
                if (s < 0) s = 0;
                float q = clamp8(rintf((float)s * r5));
                int ml = wm*64 + mt*16 + (lane>>4)*4 + r;
                Cs[ml*128 + nl] = (i8)(int)q;
            }
        }
    }
    __syncthreads();
    #pragma unroll
    for (int e=0;e<2;e++){
        int id2 = t + e*512;
        int row = id2>>3, c = id2&7;
        *(int4v*)(qout + (size_t)(m0+row)*3072 + n0 + c*16) = *(const int4v*)(Cs + row*128 + c*16);
    }
}

// fc2: q4[12544,3072] x fc2_int[768,3072]^T -> quant -> gamma2 -> +identity -> final quant -> fp32. 512 threads.
__global__ __launch_bounds__(512) void k_fc2(const char* __restrict__ ws, const float* __restrict__ act,
                                             float* __restrict__ out){
    __shared__ char smem[32768];
    const float* fws = (const float*)ws;
    const int*   iws = (const int*)ws;
    const i8* qa = (const i8*)(ws+OFF_Q4);
    const i8* wb = (const i8*)(ws+OFF_FC2);
    const int* bias = iws + WS_BF2;
    const float* g2f = fws + WS_G2F;
    const i8* x2 = (const i8*)(ws+OFF_X2);
    int m0 = blockIdx.x*128, n0 = blockIdx.y*128;
    int t = threadIdx.x, lane = t & 63;
    int w = t >> 6, wm = w & 1, wn = w >> 1;
    int4v acc[4][2]; int4v zz = {0,0,0,0};
    #pragma unroll
    for (int mt=0;mt<4;mt++) for (int nt=0;nt<2;nt++) acc[mt][nt] = zz;
    gemm_i8_512(qa, wb, 3072, 3072, m0, n0, 3072, acc, (i8*)smem, (i8*)smem+16384, t);
    float a3=act[3], a5=act[5], a6=act[6], a7=act[7];
    float wsf  = fws[WS_MAX+5]/127.0f; float r6  = (a5*wsf)/a6;
    float g2sf = fws[WS_MAX+6]/127.0f; float r7a = (a6*g2sf)/a7; float r7b = a3/a7;
    int bcol[2]; float g2v[2];
    #pragma unroll
    for (int nt=0;nt<2;nt++){
        int nc = n0 + wn*32 + nt*16 + (lane&15);
        bcol[nt] = bias[nc]; g2v[nt] = g2f[nc];
    }
    #pragma unroll
    for (int mt=0;mt<4;mt++){
        #pragma unroll
        for (int nt=0;nt<2;nt++){
            int nc = n0 + wn*32 + nt*16 + (lane&15);
            #pragma unroll
            for (int r=0;r<4;r++){
                int ml = wm*64 + mt*16 + (lane>>4)*4 + r;
                size_t gi = (size_t)(m0+ml)*768 + nc;
                int s = acc[mt][nt][r] + bcol[nt];
                float q6 = clamp8(rintf((float)s*r6));
                float o7 = q6*g2v[nt];
                float idi = (float)x2[gi];
                float tt = rintf(o7*r7a) + rintf(idi*r7b);
                tt = clamp8(tt);
                out[gi] = tt*a7;
            }
        }
    }
}

extern "C" void kernel_launch(void* const* d_in, const int* in_sizes, int n_in,
                              void* d_out, int out_size, void* d_ws, size_t ws_size,
                              hipStream_t stream){
    const float* x   = (const float*)d_in[0];
    const float* n1w = (const float*)d_in[1];
    const float* n1b = (const float*)d_in[2];
    const float* aw  = (const float*)d_in[3];
    const float* ab  = (const float*)d_in[4];
    const float* g1w = (const float*)d_in[5];
    const float* n2w = (const float*)d_in[6];
    const float* n2b = (const float*)d_in[7];
    const float* f1w = (const float*)d_in[8];
    const float* f1b = (const float*)d_in[9];
    const float* f2w = (const float*)d_in[10];
    const float* f2b = (const float*)d_in[11];
    const float* g2w = (const float*)d_in[12];
    const float* act = (const float*)d_in[13];
    char* ws = (char*)d_ws;
    float* out = (float*)d_out;

    k_init<<<16,256,0,stream>>>(ws, act, out + (size_t)B_*N_*D_);
    k_maxabs<<<dim3(120,7),256,0,stream>>>(n1w, aw, g1w, n2w, f1w, f2w, g2w, (float*)ws);
    long qwThreads = 2L*589824 + 38416 + 768L*6 + 196 + 3072 + 768;
    k_qweights<<<(int)((qwThreads+255)/256),256,0,stream>>>(n1w,n1b,aw,ab,g1w,n2w,n2b,
                                                            f1w,f1b,f2w,f2b,g2w,act,ws);
    k_stage1<<<dim3(12,4,64),256,0,stream>>>(x, ws, ws, act);
    k_attn<<<dim3(2,6,64),256,0,stream>>>(ws, act);
    k_fc1<<<dim3(98,24),512,0,stream>>>(ws, act);
    k_fc2<<<dim3(98,6),512,0,stream>>>(ws, act, out);
}

// Round 12
// 261.886 us; speedup vs baseline: 1.2802x; 1.0407x over previous
//
#include <hip/hip_runtime.h>

#define B_ 64
#define N_ 196
#define D_ 768
#define H_ 3072
#define M_ (B_*N_)   // 12544
#define NP 256       // padded token count for attn GEMM K / M

typedef int int4v __attribute__((ext_vector_type(4)));
typedef signed char i8;

// ---- workspace layout ----
#define WS_MAX 0                 // float[8]: 0 n1w,1 attn,2 g1,3 n2,4 fc1,5 fc2,6 g2
#define WS_W1F 16
#define WS_B1F (16+768)
#define WS_G1F (16+768*2)
#define WS_W2F (16+768*3)
#define WS_B2F (16+768*4)
#define WS_G2F (16+768*5)
#define WS_BA  (16+768*6)        // int[256]
#define WS_BF1 (WS_BA+256)       // int[3072]
#define WS_BF2 (WS_BF1+3072)     // int[768]
// byte offsets. GEMM operands stored CHUNK-MAJOR (CM):
//   [rblk=r/128][kblk=k/64][ksub=(k%64)/16][row=r%128][16B]
// -> staging is a linear 8KB copy; fragment ds_read phases are contiguous.
#define OFF_WA   40960ull                      // CM, 256 rows, K=256 (zero-padded)
#define OFF_FC1  (OFF_WA+65536ull)             // CM, 3072 rows, K=768
#define OFF_FC2  (OFF_FC1+2359296ull)          // CM, 768 rows, K=3072
#define OFF_X2   (OFF_FC2+2359296ull)          // i8[12544][768] row-major
#define OFF_Q3   (OFF_X2+9633792ull)           // CM, 12544 rows, K=768
#define OFF_Q4   (OFF_Q3+9633792ull)           // CM, 12544 rows, K=3072
// q1T (CM, per-batch 768 rows x K=256) and x8 alias the q4 region
#define OFF_Q1T  OFF_Q4                        // 64 x 196608 B
#define OFF_X8   (OFF_Q4+12582912ull)          // i8[12544][768] row-major rint(x/a0)

__device__ __forceinline__ float clamp8(float v){ return fminf(fmaxf(v,-128.f),127.f); }

// async global->LDS, 16B per lane. lds dest = wave-uniform base + lane*16.
__device__ __forceinline__ void async16(const void* g, void* l){
    __builtin_amdgcn_global_load_lds((const __attribute__((address_space(1))) void*)g,
                                     (__attribute__((address_space(3))) void*)l, 16, 0, 0);
}

__global__ void k_init(char* ws, const float* __restrict__ act, float* out_tail){
    int id = blockIdx.x*256 + threadIdx.x;
    if (blockIdx.x == 0){
        float* f = (float*)ws;
        if (threadIdx.x < 8) f[WS_MAX+threadIdx.x] = 0.f;
        if (threadIdx.x == 8) *out_tail = act[7];
    }
    if (id < 4096){ int4v z = {0,0,0,0}; ((int4v*)(ws+OFF_WA))[id] = z; }
}

__global__ void k_maxabs(const float* __restrict__ p0, const float* __restrict__ p1,
                         const float* __restrict__ p2, const float* __restrict__ p3,
                         const float* __restrict__ p4, const float* __restrict__ p5,
                         const float* __restrict__ p6, float* wsmax){
    const float* ps[7] = {p0,p1,p2,p3,p4,p5,p6};
    const int    n4s[7] = {192, 9604, 192, 192, 589824, 589824, 192};
    int tid = blockIdx.y;
    const float4* p = (const float4*)ps[tid]; int n4 = n4s[tid];
    float m = 0.f;
    for (int i = blockIdx.x*blockDim.x + threadIdx.x; i < n4; i += gridDim.x*blockDim.x){
        float4 v = p[i];
        m = fmaxf(m, fmaxf(fmaxf(fabsf(v.x),fabsf(v.y)), fmaxf(fabsf(v.z),fabsf(v.w))));
    }
    #pragma unroll
    for (int off = 32; off; off >>= 1) m = fmaxf(m, __shfl_down(m, off, 64));
    __shared__ float red[4];
    int lane = threadIdx.x & 63, wv = threadIdx.x >> 6;
    if (lane == 0) red[wv] = m;
    __syncthreads();
    if (threadIdx.x == 0){
        float mm = red[0];
        for (int w = 1; w < (int)blockDim.x/64; w++) mm = fmaxf(mm, red[w]);
        atomicMax((unsigned*)&wsmax[tid], __float_as_uint(mm));
    }
}

// chunk-major offset for row o, k; KC = K/64
__device__ __forceinline__ size_t cm_off(int o, int k, int KC){
    return (((size_t)(o>>7)*KC + (k>>6))<<13) + (((k>>4)&3)<<11) + ((o&127)<<4) + (k&15);
}

__global__ void k_qweights(const float* __restrict__ n1w, const float* __restrict__ n1b,
                           const float* __restrict__ aw,  const float* __restrict__ ab,
                           const float* __restrict__ g1w, const float* __restrict__ n2w,
                           const float* __restrict__ n2b, const float* __restrict__ f1w,
                           const float* __restrict__ f1b, const float* __restrict__ f2w,
                           const float* __restrict__ f2b, const float* __restrict__ g2w,
                           const float* __restrict__ act, char* ws){
    float* fws = (float*)ws;
    int*   iws = (int*)ws;
    const float* mx = fws + WS_MAX;
    long i = (long)blockIdx.x*blockDim.x + threadIdx.x;
    const long F4 = 589824;
    if (i < F4){ float sf = mx[4]/127.0f;
        float4 v = ((const float4*)f1w)[i];
        int o = (int)(i/192), kb = (int)(i%192)*4;
        unsigned b0 = (unsigned)(unsigned char)(i8)(int)fminf(fmaxf(rintf(v.x/sf),-128.f),127.f);
        unsigned b1 = (unsigned)(unsigned char)(i8)(int)fminf(fmaxf(rintf(v.y/sf),-128.f),127.f);
        unsigned b2 = (unsigned)(unsigned char)(i8)(int)fminf(fmaxf(rintf(v.z/sf),-128.f),127.f);
        unsigned b3 = (unsigned)(unsigned char)(i8)(int)fminf(fmaxf(rintf(v.w/sf),-128.f),127.f);
        *(unsigned*)(ws + OFF_FC1 + cm_off(o, kb, 12)) = b0 | (b1<<8) | (b2<<16) | (b3<<24);
        return; }
    i -= F4;
    if (i < F4){ float sf = mx[5]/127.0f;
        float4 v = ((const float4*)f2w)[i];
        int o = (int)(i/768), kb = (int)(i%768)*4;
        unsigned b0 = (unsigned)(unsigned char)(i8)(int)fminf(fmaxf(rintf(v.x/sf),-128.f),127.f);
        unsigned b1 = (unsigned)(unsigned char)(i8)(int)fminf(fmaxf(rintf(v.y/sf),-128.f),127.f);
        unsigned b2 = (unsigned)(unsigned char)(i8)(int)fminf(fmaxf(rintf(v.z/sf),-128.f),127.f);
        unsigned b3 = (unsigned)(unsigned char)(i8)(int)fminf(fmaxf(rintf(v.w/sf),-128.f),127.f);
        *(unsigned*)(ws + OFF_FC2 + cm_off(o, kb, 48)) = b0 | (b1<<8) | (b2<<16) | (b3<<24);
        return; }
    i -= F4;
    if (i < 38416){ float sf = mx[1]/127.0f;
        int o = (int)(i/196), k = (int)(i%196);
        ((i8*)(ws+OFF_WA))[cm_off(o, k, 4)] =
            (i8)(int)fminf(fmaxf(rintf(aw[i]/sf),-128.f),127.f); return; }
    i -= 38416;
    if (i < 768){ float sf = mx[0]/127.0f; fws[WS_W1F+i] = rintf(n1w[i]/sf); return; }
    i -= 768;
    if (i < 768){ float sf = mx[0]/127.0f; fws[WS_B1F+i] = rintf(n1b[i]/(act[0]*sf)); return; }
    i -= 768;
    if (i < 768){ float sf = mx[2]/127.0f; fws[WS_G1F+i] = rintf(g1w[i]/sf); return; }
    i -= 768;
    if (i < 768){ float sf = mx[3]/127.0f; fws[WS_W2F+i] = rintf(n2w[i]/sf); return; }
    i -= 768;
    if (i < 768){ float sf = mx[3]/127.0f; fws[WS_B2F+i] = rintf(n2b[i]/(act[3]*sf)); return; }
    i -= 768;
    if (i < 768){ float sf = mx[6]/127.0f; fws[WS_G2F+i] = rintf(g2w[i]/sf); return; }
    i -= 768;
    if (i < 196){ float sf = mx[1]/127.0f; iws[WS_BA+i] = (int)rintf(ab[i]/(act[1]*sf)); return; }
    i -= 196;
    if (i < 3072){ float sf = mx[4]/127.0f; iws[WS_BF1+i] = (int)rintf(f1b[i]/(act[4]*sf)); return; }
    i -= 3072;
    if (i < 768){ float sf = mx[5]/127.0f; iws[WS_BF2+i] = (int)rintf(f2b[i]/(act[5]*sf)); return; }
}

// norm1 + quant_act1 -> q1T CM (per-batch, rows=d 768, K=n 256) + x8 row-major.
__global__ __launch_bounds__(256) void k_stage1(const float* __restrict__ x,
                                                const char* __restrict__ wsc,
                                                char* __restrict__ ws,
                                                const float* __restrict__ act){
    __shared__ i8 T[64][68];
    const float* fws = (const float*)wsc;
    int b = blockIdx.z, n0 = blockIdx.y*64, d0 = blockIdx.x*64;
    int t = threadIdx.x;
    float a0 = act[0];
    float w1sf = fws[WS_MAX+0]/127.0f;
    float r1 = (a0*w1sf)/act[1];
    int dl = (t & 15) * 4;
    int d  = d0 + dl;
    float4 wv = *(const float4*)(fws + WS_W1F + d);
    float4 bv = *(const float4*)(fws + WS_B1F + d);
    i8* x8 = (i8*)(ws + OFF_X8);
    #pragma unroll
    for (int pass = 0; pass < 4; pass++){
        int nl = (t >> 4) + pass*16;
        int n  = n0 + nl;
        i8 q[4] = {0,0,0,0};
        if (n < 196){
            float4 xv = *(const float4*)(x + ((size_t)b*196 + n)*768 + d);
            float i0 = rintf(xv.x/a0), i1 = rintf(xv.y/a0);
            float i2 = rintf(xv.z/a0), i3 = rintf(xv.w/a0);
            *(char4*)(x8 + ((size_t)b*196 + n)*768 + d) =
                make_char4((i8)(int)i0,(i8)(int)i1,(i8)(int)i2,(i8)(int)i3);
            float o0 = rintf(i0*wv.x + bv.x);
            float o1 = rintf(i1*wv.y + bv.y);
            float o2 = rintf(i2*wv.z + bv.z);
            float o3 = rintf(i3*wv.w + bv.w);
            q[0] = (i8)(int)clamp8(rintf(o0*r1));
            q[1] = (i8)(int)clamp8(rintf(o1*r1));
            q[2] = (i8)(int)clamp8(rintf(o2*r1));
            q[3] = (i8)(int)clamp8(rintf(o3*r1));
        }
        T[dl+0][nl] = q[0]; T[dl+1][nl] = q[1];
        T[dl+2][nl] = q[2]; T[dl+3][nl] = q[3];
    }
    __syncthreads();
    i8* q1T = (i8*)(ws + OFF_Q1T) + (size_t)b*196608;
    #pragma unroll
    for (int e = 0; e < 4; e++){
        int id = t + e*256;
        int row = id >> 4, c = (id & 15) * 4;   // d-row local, n-col local
        int dd = d0 + row;
        int v = *(const int*)&T[row][c];
        size_t dst = (((size_t)(dd>>7)*4 + blockIdx.y)<<13) + ((size_t)(c>>4)<<11)
                     + ((dd&127)<<4) + (c&15);
        *(int*)(q1T + dst) = v;
    }
}

// CM double-buffered int8 GEMM, 512 threads: 128x128 tile, BK=64, wave tile
// 64x32 (2m x 4n). Staging = linear 8KB copies. One barrier per iter.
__device__ __forceinline__ void gemm_cm_512(const i8* __restrict__ gA, const i8* __restrict__ gB,
                                            int iters, int4v acc[4][2], i8* As, i8* Bs, int t){
    int lane = t & 63;
    int w = t >> 6, wm = w & 1, wn = w >> 1;
    int lo = t*16;
    async16(gA + lo, As + lo);
    async16(gB + lo, Bs + lo);
    int arow = (lane>>4)*2048 + (wm*64 + (lane&15))*16;
    int brow = (lane>>4)*2048 + (wn*32 + (lane&15))*16;
    for (int i = 0; i < iters; i++){
        __syncthreads();
        if (i+1 < iters){
            int nb = ((i+1)&1) << 13;
            size_t kb = (size_t)(i+1) << 13;
            async16(gA + kb + lo, As + nb + lo);
            async16(gB + kb + lo, Bs + nb + lo);
        }
        int cb = (i&1) << 13;
        int4v a[4], bb[2];
        #pragma unroll
        for (int mt = 0; mt < 4; mt++)
            a[mt] = *(const int4v*)(As + cb + arow + mt*256);
        #pragma unroll
        for (int nt = 0; nt < 2; nt++)
            bb[nt] = *(const int4v*)(Bs + cb + brow + nt*256);
        #pragma unroll
        for (int mt = 0; mt < 4; mt++)
            #pragma unroll
            for (int nt = 0; nt < 2; nt++)
                acc[mt][nt] = __builtin_amdgcn_mfma_i32_16x16x64_i8(a[mt], bb[nt], acc[mt][nt], 0,0,0);
    }
}

// CM double-buffered int8 GEMM, 256 threads: 128x128 tile, wave tile 64x64.
__device__ __forceinline__ void gemm_cm_256(const i8* __restrict__ gA, const i8* __restrict__ gB,
                                            int iters, int4v acc[4][4], i8* As, i8* Bs, int t){
    int lane = t & 63;
    int wm = (t>>6)&1, wn = t>>7;
    int lo = t*16;
    async16(gA + lo,        As + lo);
    async16(gA + 4096 + lo, As + 4096 + lo);
    async16(gB + lo,        Bs + lo);
    async16(gB + 4096 + lo, Bs + 4096 + lo);
    int arow = (lane>>4)*2048 + (wm*64 + (lane&15))*16;
    int brow = (lane>>4)*2048 + (wn*64 + (lane&15))*16;
    for (int i = 0; i < iters; i++){
        __syncthreads();
        if (i+1 < iters){
            int nb = ((i+1)&1) << 13;
            size_t kb = (size_t)(i+1) << 13;
            async16(gA + kb + lo,        As + nb + lo);
            async16(gA + kb + 4096 + lo, As + nb + 4096 + lo);
            async16(gB + kb + lo,        Bs + nb + lo);
            async16(gB + kb + 4096 + lo, Bs + nb + 4096 + lo);
        }
        int cb = (i&1) << 13;
        int4v a[4], bb[4];
        #pragma unroll
        for (int mt = 0; mt < 4; mt++)
            a[mt] = *(const int4v*)(As + cb + arow + mt*256);
        #pragma unroll
        for (int nt = 0; nt < 4; nt++)
            bb[nt] = *(const int4v*)(Bs + cb + brow + nt*256);
        #pragma unroll
        for (int mt = 0; mt < 4; mt++)
            #pragma unroll
            for (int nt = 0; nt < 4; nt++)
                acc[mt][nt] = __builtin_amdgcn_mfma_i32_16x16x64_i8(a[mt], bb[nt], acc[mt][nt], 0,0,0);
    }
}

// attn (4 waves): CM operands; epilogue -> x2 row-major, q3 CM.
__global__ __launch_bounds__(256) void k_attn(const char* __restrict__ ws,
                                              const float* __restrict__ act){
    __shared__ char smem[32768];
    const float* fws = (const float*)ws;
    const int*   iws = (const int*)ws;
    int b = blockIdx.z;
    int m0 = blockIdx.x*128, n0 = blockIdx.y*128;
    const i8* gA = (const i8*)(ws + OFF_WA)  + ((size_t)(m0>>7))*32768;
    const i8* gB = (const i8*)(ws + OFF_Q1T) + (size_t)b*196608 + ((size_t)(n0>>7))*32768;
    const i8* x8 = (const i8*)(ws + OFF_X8);
    i8* x2  = (i8*)(ws + OFF_X2);
    i8* q3  = (i8*)(ws + OFF_Q3);
    int t = threadIdx.x, lane = t & 63;
    int wm = (t>>6)&1, wn = t>>7;
    int4v acc[4][4]; int4v zz = {0,0,0,0};
    #pragma unroll
    for (int mt=0;mt<4;mt++) for (int nt=0;nt<4;nt++) acc[mt][nt] = zz;
    gemm_cm_256(gA, gB, 4, acc, (i8*)smem, (i8*)smem+16384, t);

    float a1=act[1], a2=act[2], a3=act[3], a4=act[4];
    float wasf = fws[WS_MAX+1]/127.0f; float r2  = (a1*wasf)/a2;
    float g1sf = fws[WS_MAX+2]/127.0f; float r3a = (a2*g1sf)/a3; float r3b = act[0]/a3;
    float w2sf = fws[WS_MAX+3]/127.0f; float r4  = (a3*w2sf)/a4;
    float g1v[4], w2v[4], b2v[4];
    #pragma unroll
    for (int nt=0;nt<4;nt++){
        int d = n0 + wn*64 + nt*16 + (lane&15);
        g1v[nt] = fws[WS_G1F + d]; w2v[nt] = fws[WS_W2F + d]; b2v[nt] = fws[WS_B2F + d];
    }
    __syncthreads();
    i8* Xs = (i8*)smem;
    i8* Qs = (i8*)smem + 16384;
    #pragma unroll
    for (int mt=0;mt<4;mt++){
        #pragma unroll
        for (int r=0;r<4;r++){
            int ml = wm*64 + mt*16 + (lane>>4)*4 + r;
            int o  = m0 + ml;
            int ba = iws[WS_BA + o];
            #pragma unroll
            for (int nt=0;nt<4;nt++){
                int nl = wn*64 + nt*16 + (lane&15);
                int d  = n0 + nl;
                float s2 = (float)(acc[mt][nt][r] + ba);
                float q2 = clamp8(rintf(s2*r2));
                float o3v = q2*g1v[nt];
                float idi = (o < 196) ? (float)x8[((size_t)b*196 + o)*768 + d] : 0.f;
                float tt = rintf(o3v*r3a) + rintf(idi*r3b);
                tt = clamp8(tt);
                float o4 = tt*w2v[nt] + b2v[nt];
                float qr = clamp8(rintf(o4*r4));
                Xs[ml*128 + nl] = (i8)(int)tt;
                Qs[ml*128 + nl] = (i8)(int)qr;
            }
        }
    }
    __syncthreads();
    #pragma unroll
    for (int e=0;e<4;e++){
        int id = t + e*256;
        int row = id>>3, c = id&7;
        int o = m0 + row;
        if (o < 196){
            int rg = b*196 + o;
            size_t g = (size_t)rg*768 + n0 + c*16;
            *(int4v*)(x2 + g) = *(const int4v*)(Xs + row*128 + c*16);
            size_t dst = (((size_t)(rg>>7)*12 + (n0>>6) + (c>>2))<<13)
                         + ((size_t)(c&3)<<11) + ((rg&127)<<4);
            *(int4v*)(q3 + dst) = *(const int4v*)(Qs + row*128 + c*16);
        }
    }
}

// fc1: q3(CM) x fc1(CM) -> relu -> quant -> q4(CM). 512 threads.
__global__ __launch_bounds__(512) void k_fc1(const char* __restrict__ ws, const float* __restrict__ act){
    __shared__ char smem[32768];
    const float* fws = (const float*)ws;
    const int*   iws = (const int*)ws;
    int m0 = blockIdx.x*128, n0 = blockIdx.y*128;
    const i8* gA = (const i8*)(ws+OFF_Q3)  + ((size_t)blockIdx.x)*12*8192;
    const i8* gB = (const i8*)(ws+OFF_FC1) + ((size_t)blockIdx.y)*12*8192;
    const int* bias = iws + WS_BF1;
    i8* q4 = (i8*)(ws+OFF_Q4);
    int t = threadIdx.x, lane = t & 63;
    int w = t >> 6, wm = w & 1, wn = w >> 1;
    int4v acc[4][2]; int4v zz = {0,0,0,0};
    #pragma unroll
    for (int mt=0;mt<4;mt++) for (int nt=0;nt<2;nt++) acc[mt][nt] = zz;
    gemm_cm_512(gA, gB, 12, acc, (i8*)smem, (i8*)smem+16384, t);
    float wsf = fws[WS_MAX+4]/127.0f;
    float r5 = (act[4]*wsf)/act[5];
    int bcol[2];
    #pragma unroll
    for (int nt=0;nt<2;nt++) bcol[nt] = bias[n0 + wn*32 + nt*16 + (lane&15)];
    __syncthreads();
    i8* Cs = (i8*)smem;
    #pragma unroll
    for (int mt=0;mt<4;mt++){
        #pragma unroll
        for (int nt=0;nt<2;nt++){
            int nl = wn*32 + nt*16 + (lane&15);
            #pragma unroll
            for (int r=0;r<4;r++){
                int s = acc[mt][nt][r] + bcol[nt];
                if (s < 0) s = 0;
                float q = clamp8(rintf((float)s * r5));
                int ml = wm*64 + mt*16 + (lane>>4)*4 + r;
                Cs[ml*128 + nl] = (i8)(int)q;
            }
        }
    }
    __syncthreads();
    #pragma unroll
    for (int e=0;e<2;e++){
        int id = t + e*512;
        int row = id>>3, c = id&7;
        size_t dst = (((size_t)blockIdx.x*48 + (n0>>6) + (c>>2))<<13)
                     + ((size_t)(c&3)<<11) + ((size_t)row<<4);
        *(int4v*)(q4 + dst) = *(const int4v*)(Cs + row*128 + c*16);
    }
}

// fc2: q4(CM) x fc2(CM) -> quant -> gamma2 -> +identity -> final quant -> fp32. 512 threads.
__global__ __launch_bounds__(512) void k_fc2(const char* __restrict__ ws, const float* __restrict__ act,
                                             float* __restrict__ out){
    __shared__ char smem[32768];
    const float* fws = (const float*)ws;
    const int*   iws = (const int*)ws;
    int m0 = blockIdx.x*128, n0 = blockIdx.y*128;
    const i8* gA = (const i8*)(ws+OFF_Q4)  + ((size_t)blockIdx.x)*48*8192;
    const i8* gB = (const i8*)(ws+OFF_FC2) + ((size_t)blockIdx.y)*48*8192;
    const int* bias = iws + WS_BF2;
    const float* g2f = fws + WS_G2F;
    const i8* x2 = (const i8*)(ws+OFF_X2);
    int t = threadIdx.x, lane = t & 63;
    int w = t >> 6, wm = w & 1, wn = w >> 1;
    int4v acc[4][2]; int4v zz = {0,0,0,0};
    #pragma unroll
    for (int mt=0;mt<4;mt++) for (int nt=0;nt<2;nt++) acc[mt][nt] = zz;
    gemm_cm_512(gA, gB, 48, acc, (i8*)smem, (i8*)smem+16384, t);
    float a3=act[3], a5=act[5], a6=act[6], a7=act[7];
    float wsf  = fws[WS_MAX+5]/127.0f; float r6  = (a5*wsf)/a6;
    float g2sf = fws[WS_MAX+6]/127.0f; float r7a = (a6*g2sf)/a7; float r7b = a3/a7;
    int bcol[2]; float g2v[2];
    #pragma unroll
    for (int nt=0;nt<2;nt++){
        int nc = n0 + wn*32 + nt*16 + (lane&15);
        bcol[nt] = bias[nc]; g2v[nt] = g2f[nc];
    }
    #pragma unroll
    for (int mt=0;mt<4;mt++){
        #pragma unroll
        for (int nt=0;nt<2;nt++){
            int nc = n0 + wn*32 + nt*16 + (lane&15);
            #pragma unroll
            for (int r=0;r<4;r++){
                int ml = wm*64 + mt*16 + (lane>>4)*4 + r;
                size_t gi = (size_t)(m0+ml)*768 + nc;
                int s = acc[mt][nt][r] + bcol[nt];
                float q6 = clamp8(rintf((float)s*r6));
                float o7 = q6*g2v[nt];
                float idi = (float)x2[gi];
                float tt = rintf(o7*r7a) + rintf(idi*r7b);
                tt = clamp8(tt);
                out[gi] = tt*a7;
            }
        }
    }
}

extern "C" void kernel_launch(void* const* d_in, const int* in_sizes, int n_in,
                              void* d_out, int out_size, void* d_ws, size_t ws_size,
                              hipStream_t stream){
    const float* x   = (const float*)d_in[0];
    const float* n1w = (const float*)d_in[1];
    const float* n1b = (const float*)d_in[2];
    const float* aw  = (const float*)d_in[3];
    const float* ab  = (const float*)d_in[4];
    const float* g1w = (const float*)d_in[5];
    const float* n2w = (const float*)d_in[6];
    const float* n2b = (const float*)d_in[7];
    const float* f1w = (const float*)d_in[8];
    const float* f1b = (const float*)d_in[9];
    const float* f2w = (const float*)d_in[10];
    const float* f2b = (const float*)d_in[11];
    const float* g2w = (const float*)d_in[12];
    const float* act = (const float*)d_in[13];
    char* ws = (char*)d_ws;
    float* out = (float*)d_out;

    k_init<<<16,256,0,stream>>>(ws, act, out + (size_t)B_*N_*D_);
    k_maxabs<<<dim3(120,7),256,0,stream>>>(n1w, aw, g1w, n2w, f1w, f2w, g2w, (float*)ws);
    long qwThreads = 2L*589824 + 38416 + 768L*6 + 196 + 3072 + 768;
    k_qweights<<<(int)((qwThreads+255)/256),256,0,stream>>>(n1w,n1b,aw,ab,g1w,n2w,n2b,
                                                            f1w,f1b,f2w,f2b,g2w,act,ws);
    k_stage1<<<dim3(12,4,64),256,0,stream>>>(x, ws, ws, act);
    k_attn<<<dim3(2,6,64),256,0,stream>>>(ws, act);
    k_fc1<<<dim3(98,24),512,0,stream>>>(ws, act);
    k_fc2<<<dim3(98,6),512,0,stream>>>(ws, act, out);
}